// Round 4
// baseline (49.204 us; speedup 1.0000x reference)
//
#include <hip/hip_runtime.h>

#define X_DIM 5
#define Y_DIM 2
#define H1 560
#define H2 40
#define GRUH 145
#define G3 435    // 3*GRUH

__device__ __forceinline__ float wave_reduce(float v) {
#pragma unroll
    for (int off = 32; off > 0; off >>= 1)
        v += __shfl_xor(v, off, 64);
    return v;
}

__device__ __forceinline__ float sigmoidf_(float x) {
    return 1.0f / (1.0f + __expf(-x));
}

// Entire network in ONE block (1024 threads, 16 waves) on one CU.
// All inter-stage state in LDS; only __syncthreads() between stages.
// ~1.79 MB of weights stream from L2 (resident across replays).
__global__ __launch_bounds__(1024) void fused_one_block(
    const float* __restrict__ si, const float* __restrict__ oi,
    const float* __restrict__ dst, const float* __restrict__ dob,
    const float* __restrict__ W1, const float* __restrict__ b1,
    const float* __restrict__ Wih0, const float* __restrict__ Whh0,
    const float* __restrict__ bih0, const float* __restrict__ bhh0,
    const float* __restrict__ Wih1, const float* __restrict__ Whh1,
    const float* __restrict__ bih1, const float* __restrict__ bhh1,
    const float* __restrict__ W2a, const float* __restrict__ b2a,
    const float* __restrict__ W2b, const float* __restrict__ b2b,
    const float* __restrict__ hn, float* __restrict__ out)
{
    __shared__ float sx[14];
    __shared__ float shn[2 * GRUH];
    __shared__ __align__(16) float sl1[H1];
    __shared__ float sgi0[G3];       // reused as gi1 in stage C
    __shared__ float sgh0[G3];
    __shared__ float sgh1[G3];
    __shared__ __align__(16) float sh0[GRUH];
    __shared__ float sh1[GRUH];
    __shared__ float sl2h[H2];

    const int tid  = threadIdx.x;
    const int w    = tid >> 6;    // wave 0..15
    const int lane = tid & 63;

    // ---- stage inputs into LDS ----
    if (tid < X_DIM)       sx[tid] = si[tid];
    else if (tid < 7)      sx[tid] = oi[tid - 5];
    else if (tid < 12)     sx[tid] = dst[tid - 7];
    else if (tid < 14)     sx[tid] = dob[tid - 12];
    if (tid >= 64 && tid < 64 + 2 * GRUH) shn[tid - 64] = hn[tid - 64];
    __syncthreads();

    // ---- l1 = relu(W1 @ x + b1): thread-per-row ----
    for (int j = tid; j < H1; j += 1024) {
        float a = b1[j];
        const float* wp = W1 + j * 14;
#pragma unroll
        for (int k = 0; k < 14; ++k) a = fmaf(wp[k], sx[k], a);
        sl1[j] = fmaxf(a, 0.0f);
    }
    __syncthreads();

    // ---- gi0 = Wih0 @ l1 (435 rows x 560): 4 contiguous rows per wave-iter,
    //      float4 loads (row stride 2240 B is 16B-aligned) ----
    for (int base = w * 4; base < G3; base += 64) {
        float a0 = 0.f, a1 = 0.f, a2 = 0.f, a3 = 0.f;
        const int nr = (G3 - base < 4) ? (G3 - base) : 4;
        if (nr == 4) {
            const float4* r0 = reinterpret_cast<const float4*>(Wih0 + (base + 0) * H1);
            const float4* r1 = reinterpret_cast<const float4*>(Wih0 + (base + 1) * H1);
            const float4* r2 = reinterpret_cast<const float4*>(Wih0 + (base + 2) * H1);
            const float4* r3 = reinterpret_cast<const float4*>(Wih0 + (base + 3) * H1);
            for (int k = lane; k * 4 < H1; k += 64) {
                const float4 xv = *reinterpret_cast<const float4*>(&sl1[k * 4]);
                const float4 w0 = r0[k], w1 = r1[k], w2 = r2[k], w3 = r3[k];
                a0 = fmaf(w0.x, xv.x, fmaf(w0.y, xv.y, fmaf(w0.z, xv.z, fmaf(w0.w, xv.w, a0))));
                a1 = fmaf(w1.x, xv.x, fmaf(w1.y, xv.y, fmaf(w1.z, xv.z, fmaf(w1.w, xv.w, a1))));
                a2 = fmaf(w2.x, xv.x, fmaf(w2.y, xv.y, fmaf(w2.z, xv.z, fmaf(w2.w, xv.w, a2))));
                a3 = fmaf(w3.x, xv.x, fmaf(w3.y, xv.y, fmaf(w3.z, xv.z, fmaf(w3.w, xv.w, a3))));
            }
        } else {
            for (int j = 0; j < nr; ++j) {
                float a = 0.f;
                const float* rp = Wih0 + (base + j) * H1;
                for (int k = lane; k < H1; k += 64) a = fmaf(rp[k], sl1[k], a);
                if (j == 0) a0 = a; else if (j == 1) a1 = a; else a2 = a;
            }
        }
        a0 = wave_reduce(a0); a1 = wave_reduce(a1);
        a2 = wave_reduce(a2); a3 = wave_reduce(a3);
        if (lane == 0) {
            sgi0[base] = a0;
            if (base + 1 < G3) sgi0[base + 1] = a1;
            if (base + 2 < G3) sgi0[base + 2] = a2;
            if (base + 3 < G3) sgi0[base + 3] = a3;
        }
    }

    // ---- gh0 = Whh0 @ hn0, gh1 = Whh1 @ hn1 (870 rows x 145):
    //      8 rows per wave-iter, scalar coalesced loads ----
    for (int base = w * 8; base < 2 * G3; base += 128) {
        float acc[8];
        const float* wp[8];
        bool is0[8];
#pragma unroll
        for (int m = 0; m < 8; ++m) {
            acc[m] = 0.f;
            const int rr = base + m;
            const int rc = (rr < 2 * G3) ? rr : (2 * G3 - 1);
            is0[m] = (rc < G3);
            wp[m] = is0[m] ? (Whh0 + rc * GRUH) : (Whh1 + (rc - G3) * GRUH);
        }
        for (int k = lane; k < GRUH; k += 64) {
            const float x0 = shn[k], x1 = shn[GRUH + k];
#pragma unroll
            for (int m = 0; m < 8; ++m)
                acc[m] = fmaf(wp[m][k], is0[m] ? x0 : x1, acc[m]);
        }
#pragma unroll
        for (int m = 0; m < 8; ++m) acc[m] = wave_reduce(acc[m]);
        if (lane == 0) {
#pragma unroll
            for (int m = 0; m < 8; ++m) {
                const int rr = base + m;
                if (rr < G3) sgh0[rr] = acc[m];
                else if (rr < 2 * G3) sgh1[rr - G3] = acc[m];
            }
        }
    }
    __syncthreads();

    // ---- combine h0 (threads 0..144) ----
    if (tid < GRUH) {
        const int e = tid;
        const float gr = sgi0[e] + bih0[e] + sgh0[e] + bhh0[e];
        const float gz = sgi0[e + GRUH] + bih0[e + GRUH] + sgh0[e + GRUH] + bhh0[e + GRUH];
        const float r = sigmoidf_(gr);
        const float z = sigmoidf_(gz);
        const float n = tanhf(sgi0[e + 2 * GRUH] + bih0[e + 2 * GRUH]
                              + r * (sgh0[e + 2 * GRUH] + bhh0[e + 2 * GRUH]));
        sh0[e] = (1.0f - z) * n + z * shn[e];
    }
    __syncthreads();

    // ---- gi1 = Wih1 @ h0 (435 rows x 145): 8 rows per wave-iter ----
    for (int base = w * 8; base < G3; base += 128) {
        float acc[8];
        const float* wp[8];
#pragma unroll
        for (int m = 0; m < 8; ++m) {
            acc[m] = 0.f;
            const int rc = (base + m < G3) ? (base + m) : (G3 - 1);
            wp[m] = Wih1 + rc * GRUH;
        }
        for (int k = lane; k < GRUH; k += 64) {
            const float x = sh0[k];
#pragma unroll
            for (int m = 0; m < 8; ++m)
                acc[m] = fmaf(wp[m][k], x, acc[m]);
        }
#pragma unroll
        for (int m = 0; m < 8; ++m) acc[m] = wave_reduce(acc[m]);
        if (lane == 0) {
#pragma unroll
            for (int m = 0; m < 8; ++m)
                if (base + m < G3) sgi0[base + m] = acc[m];   // reuse sgi0 as gi1
        }
    }
    __syncthreads();

    // ---- combine h1 (threads 0..144) ----
    if (tid < GRUH) {
        const int e = tid;
        const float gr = sgi0[e] + bih1[e] + sgh1[e] + bhh1[e];
        const float gz = sgi0[e + GRUH] + bih1[e + GRUH] + sgh1[e + GRUH] + bhh1[e + GRUH];
        const float r = sigmoidf_(gr);
        const float z = sigmoidf_(gz);
        const float n = tanhf(sgi0[e + 2 * GRUH] + bih1[e + 2 * GRUH]
                              + r * (sgh1[e + 2 * GRUH] + bhh1[e + 2 * GRUH]));
        sh1[e] = (1.0f - z) * n + z * shn[GRUH + e];
    }
    __syncthreads();

    // ---- l2 head: relu(W2a@h1+b2a) then W2b@. + b2b ----
    for (int row = w; row < H2; row += 16) {
        float a = 0.f;
        const float* rp = W2a + row * GRUH;
        for (int k = lane; k < GRUH; k += 64) a = fmaf(rp[k], sh1[k], a);
        a = wave_reduce(a);
        if (lane == 0) sl2h[row] = fmaxf(a + b2a[row], 0.0f);
    }
    __syncthreads();
    if (tid < X_DIM * Y_DIM) {
        float a = b2b[tid];
        const float* rp = W2b + tid * H2;
#pragma unroll
        for (int k = 0; k < H2; ++k) a = fmaf(rp[k], sl2h[k], a);
        out[tid] = a;
    }
}

extern "C" void kernel_launch(void* const* d_in, const int* in_sizes, int n_in,
                              void* d_out, int out_size, void* d_ws, size_t ws_size,
                              hipStream_t stream) {
    const float* si   = (const float*)d_in[0];
    const float* oi   = (const float*)d_in[1];
    const float* dst  = (const float*)d_in[2];
    const float* dob  = (const float*)d_in[3];
    const float* W1   = (const float*)d_in[4];
    const float* b1   = (const float*)d_in[5];
    const float* Wih0 = (const float*)d_in[6];
    const float* Whh0 = (const float*)d_in[7];
    const float* bih0 = (const float*)d_in[8];
    const float* bhh0 = (const float*)d_in[9];
    const float* Wih1 = (const float*)d_in[10];
    const float* Whh1 = (const float*)d_in[11];
    const float* bih1 = (const float*)d_in[12];
    const float* bhh1 = (const float*)d_in[13];
    const float* W2a  = (const float*)d_in[14];
    const float* b2a  = (const float*)d_in[15];
    const float* W2b  = (const float*)d_in[16];
    const float* b2b  = (const float*)d_in[17];
    const float* hn   = (const float*)d_in[18];

    hipLaunchKernelGGL(fused_one_block, dim3(1), dim3(1024), 0, stream,
                       si, oi, dst, dob, W1, b1, Wih0, Whh0, bih0, bhh0,
                       Wih1, Whh1, bih1, bhh1, W2a, b2a, W2b, b2b, hn,
                       (float*)d_out);
}

// Round 5
// 17.432 us; speedup vs baseline: 2.8227x; 2.8227x over previous
//
#include <hip/hip_runtime.h>

#define X_DIM 5
#define Y_DIM 2
#define H1 560
#define H2 40
#define GRUH 145
#define G3 435            // 3*GRUH
#define NB_H0 37          // blocks computing h0 in K1
#define NB_GH1 109        // blocks computing gh1 rows in K1 (109*4=436>=435)
#define NB_K2 37          // K2 blocks (37*4=148>=145)

__device__ __forceinline__ float wave_reduce(float v) {
#pragma unroll
    for (int off = 32; off > 0; off >>= 1)
        v += __shfl_xor(v, off, 64);
    return v;
}

__device__ __forceinline__ float sigmoidf_(float x) {
    return 1.0f / (1.0f + __expf(-x));
}

// K1: blocks [0,37): l1 (redundant, LDS) then h0 elements (wave-per-element).
//     blocks [37,146): gh1 = Whh1 @ hn1 + bhh1 (wave-per-row).
//     Block 37 also resets the K2 done-counter (visible to K2 via stream order).
__global__ __launch_bounds__(256) void k1_gru0(
    const float* __restrict__ si, const float* __restrict__ oi,
    const float* __restrict__ dst, const float* __restrict__ dob,
    const float* __restrict__ W1, const float* __restrict__ b1,
    const float* __restrict__ Wih0, const float* __restrict__ Whh0,
    const float* __restrict__ bih0, const float* __restrict__ bhh0,
    const float* __restrict__ Whh1, const float* __restrict__ bhh1,
    const float* __restrict__ hn,
    unsigned* __restrict__ ctr,
    float* __restrict__ h0g, float* __restrict__ gh1g)
{
    __shared__ float sx[14];
    __shared__ __align__(16) float sl1[H1];
    __shared__ float shn[GRUH];

    const int tid = threadIdx.x;
    const int wid = tid >> 6, lane = tid & 63;

    if (blockIdx.x < NB_H0) {
        if (tid < X_DIM)                      sx[tid] = si[tid];
        else if (tid < X_DIM + Y_DIM)         sx[tid] = oi[tid - X_DIM];
        else if (tid < 2 * X_DIM + Y_DIM)     sx[tid] = dst[tid - X_DIM - Y_DIM];
        else if (tid < 2 * X_DIM + 2 * Y_DIM) sx[tid] = dob[tid - 2 * X_DIM - Y_DIM];
        if (tid >= 64 && tid < 64 + GRUH) shn[tid - 64] = hn[tid - 64];   // hn layer 0
        __syncthreads();

        // l1 = relu(W1 @ x + b1)
        for (int j = tid; j < H1; j += 256) {
            float a = b1[j];
            const float* wp = W1 + j * 14;
#pragma unroll
            for (int k = 0; k < 14; ++k) a = fmaf(wp[k], sx[k], a);
            sl1[j] = fmaxf(a, 0.0f);
        }
        __syncthreads();

        const int e = blockIdx.x * 4 + wid;
        if (e < GRUH) {
            // gi0 rows e, e+145, e+290 over l1 (float4: row stride 2240B, 16B-aligned)
            float a0 = 0.f, a1 = 0.f, a2 = 0.f;
            const float4* r0 = reinterpret_cast<const float4*>(Wih0 + (e           ) * H1);
            const float4* r1 = reinterpret_cast<const float4*>(Wih0 + (e +   GRUH  ) * H1);
            const float4* r2 = reinterpret_cast<const float4*>(Wih0 + (e + 2 * GRUH) * H1);
            for (int k = lane; k * 4 < H1; k += 64) {
                const float4 xv = *reinterpret_cast<const float4*>(&sl1[k * 4]);
                const float4 w0 = r0[k], w1 = r1[k], w2 = r2[k];
                a0 = fmaf(w0.x, xv.x, fmaf(w0.y, xv.y, fmaf(w0.z, xv.z, fmaf(w0.w, xv.w, a0))));
                a1 = fmaf(w1.x, xv.x, fmaf(w1.y, xv.y, fmaf(w1.z, xv.z, fmaf(w1.w, xv.w, a1))));
                a2 = fmaf(w2.x, xv.x, fmaf(w2.y, xv.y, fmaf(w2.z, xv.z, fmaf(w2.w, xv.w, a2))));
            }
            // gh0 rows over hn0
            float a3 = 0.f, a4 = 0.f, a5 = 0.f;
            for (int k = lane; k < GRUH; k += 64) {
                const float hv = shn[k];
                a3 = fmaf(Whh0[(e           ) * GRUH + k], hv, a3);
                a4 = fmaf(Whh0[(e +   GRUH  ) * GRUH + k], hv, a4);
                a5 = fmaf(Whh0[(e + 2 * GRUH) * GRUH + k], hv, a5);
            }
            a0 = wave_reduce(a0); a1 = wave_reduce(a1); a2 = wave_reduce(a2);
            a3 = wave_reduce(a3); a4 = wave_reduce(a4); a5 = wave_reduce(a5);
            if (lane == 0) {
                const float r = sigmoidf_(a0 + bih0[e]            + a3 + bhh0[e]);
                const float z = sigmoidf_(a1 + bih0[e + GRUH]     + a4 + bhh0[e + GRUH]);
                const float n = tanhf   (a2 + bih0[e + 2 * GRUH] + r * (a5 + bhh0[e + 2 * GRUH]));
                h0g[e] = (1.0f - z) * n + z * shn[e];
            }
        }
    } else {
        if (blockIdx.x == NB_H0 && tid == 0)
            __hip_atomic_store(ctr, 0u, __ATOMIC_RELAXED, __HIP_MEMORY_SCOPE_AGENT);
        if (tid < GRUH) shn[tid] = hn[GRUH + tid];   // hn layer 1
        __syncthreads();

        const int r = (blockIdx.x - NB_H0) * 4 + wid;
        if (r < G3) {
            float a = 0.f;
            const float* rp = Whh1 + r * GRUH;
            for (int k = lane; k < GRUH; k += 64)
                a = fmaf(rp[k], shn[k], a);
            a = wave_reduce(a);
            if (lane == 0) gh1g[r] = a + bhh1[r];
        }
    }
}

// K2: 37 blocks x 256. Wave-per-element h1; per-element RELEASE stores;
// one fetch_add(ACQ_REL); only the LAST block (no spinning) acquires h1 and
// runs the l2 head.
__global__ __launch_bounds__(256) void k2_gru1_head(
    const float* __restrict__ Wih1, const float* __restrict__ bih1,
    const float* __restrict__ W2a, const float* __restrict__ b2a,
    const float* __restrict__ W2b, const float* __restrict__ b2b,
    const float* __restrict__ hn,
    const float* __restrict__ h0g, const float* __restrict__ gh1g,
    unsigned* __restrict__ ctr,
    float* __restrict__ h1g, float* __restrict__ out)
{
    __shared__ float sh0[GRUH];
    __shared__ float sh1[GRUH];
    __shared__ float sl2h[H2];
    __shared__ unsigned slast;

    const int tid = threadIdx.x;
    const int wid = tid >> 6, lane = tid & 63;
    const int e = blockIdx.x * 4 + wid;

    if (tid < GRUH) sh0[tid] = h0g[tid];
    __syncthreads();

    if (e < GRUH) {
        float c0 = 0.f, c1 = 0.f, c2 = 0.f;
        for (int k = lane; k < GRUH; k += 64) {
            const float hv = sh0[k];
            c0 = fmaf(Wih1[(e           ) * GRUH + k], hv, c0);
            c1 = fmaf(Wih1[(e +   GRUH  ) * GRUH + k], hv, c1);
            c2 = fmaf(Wih1[(e + 2 * GRUH) * GRUH + k], hv, c2);
        }
        c0 = wave_reduce(c0); c1 = wave_reduce(c1); c2 = wave_reduce(c2);
        if (lane == 0) {
            const float r = sigmoidf_(c0 + bih1[e]            + gh1g[e]);
            const float z = sigmoidf_(c1 + bih1[e + GRUH]     + gh1g[e + GRUH]);
            const float n = tanhf   (c2 + bih1[e + 2 * GRUH] + r * gh1g[e + 2 * GRUH]);
            const float v = (1.0f - z) * n + z * hn[GRUH + e];
            __hip_atomic_store(&h1g[e], v, __ATOMIC_RELEASE, __HIP_MEMORY_SCOPE_AGENT);
        }
    }
    __syncthreads();
    if (tid == 0) {
        const unsigned old =
            __hip_atomic_fetch_add(ctr, 1u, __ATOMIC_ACQ_REL, __HIP_MEMORY_SCOPE_AGENT);
        slast = (old == NB_K2 - 1u) ? 1u : 0u;
    }
    __syncthreads();
    if (!slast) return;

    // ---- last block only: l2 head ----
    for (int j = tid; j < GRUH; j += 256)
        sh1[j] = __hip_atomic_load(&h1g[j], __ATOMIC_ACQUIRE, __HIP_MEMORY_SCOPE_AGENT);
    __syncthreads();

    // W2a: 40 rows x 145; 2 rows per wave-iter for load pipelining
    for (int row = wid * 2; row < H2; row += 8) {
        float a0 = 0.f, a1 = 0.f;
        const float* rp0 = W2a + row * GRUH;
        const float* rp1 = W2a + (row + 1) * GRUH;
        for (int k = lane; k < GRUH; k += 64) {
            const float hv = sh1[k];
            a0 = fmaf(rp0[k], hv, a0);
            a1 = fmaf(rp1[k], hv, a1);
        }
        a0 = wave_reduce(a0); a1 = wave_reduce(a1);
        if (lane == 0) {
            sl2h[row]     = fmaxf(a0 + b2a[row],     0.0f);
            sl2h[row + 1] = fmaxf(a1 + b2a[row + 1], 0.0f);
        }
    }
    __syncthreads();
    if (tid < X_DIM * Y_DIM) {
        float a = b2b[tid];
        const float* rp = W2b + tid * H2;
#pragma unroll
        for (int k = 0; k < H2; ++k) a = fmaf(rp[k], sl2h[k], a);
        out[tid] = a;
    }
}

extern "C" void kernel_launch(void* const* d_in, const int* in_sizes, int n_in,
                              void* d_out, int out_size, void* d_ws, size_t ws_size,
                              hipStream_t stream) {
    const float* si   = (const float*)d_in[0];
    const float* oi   = (const float*)d_in[1];
    const float* dst  = (const float*)d_in[2];
    const float* dob  = (const float*)d_in[3];
    const float* W1   = (const float*)d_in[4];
    const float* b1   = (const float*)d_in[5];
    const float* Wih0 = (const float*)d_in[6];
    const float* Whh0 = (const float*)d_in[7];
    const float* bih0 = (const float*)d_in[8];
    const float* bhh0 = (const float*)d_in[9];
    const float* Wih1 = (const float*)d_in[10];
    const float* Whh1 = (const float*)d_in[11];
    const float* bih1 = (const float*)d_in[12];
    const float* bhh1 = (const float*)d_in[13];
    const float* W2a  = (const float*)d_in[14];
    const float* b2a  = (const float*)d_in[15];
    const float* W2b  = (const float*)d_in[16];
    const float* b2b  = (const float*)d_in[17];
    const float* hn   = (const float*)d_in[18];

    float* ws = (float*)d_ws;
    unsigned* ctr = (unsigned*)d_ws;   // 1 cache line
    float* h0g  = ws + 64;             // 145 floats
    float* gh1g = ws + 64 + 256;       // 435 floats
    float* h1g  = ws + 64 + 256 + 512; // 145 floats

    hipLaunchKernelGGL(k1_gru0, dim3(NB_H0 + NB_GH1), dim3(256), 0, stream,
                       si, oi, dst, dob, W1, b1, Wih0, Whh0, bih0, bhh0,
                       Whh1, bhh1, hn, ctr, h0g, gh1g);
    hipLaunchKernelGGL(k2_gru1_head, dim3(NB_K2), dim3(256), 0, stream,
                       Wih1, bih1, W2a, b2a, W2b, b2b, hn, h0g, gh1g,
                       ctr, h1g, (float*)d_out);
}

// Round 6
// 16.334 us; speedup vs baseline: 3.0123x; 1.0672x over previous
//
#include <hip/hip_runtime.h>

#define X_DIM 5
#define Y_DIM 2
#define H1 560
#define H2 40
#define GRUH 145
#define G3 435            // 3*GRUH
#define NB_H0 37          // K1 blocks computing h0 (37*4 waves >= 145)
#define NB_GH1 109        // K1 blocks computing gh1 rows (109*4 = 436 >= 435)
#define NB_K2 37          // K2 blocks

__device__ __forceinline__ float wave_reduce(float v) {
#pragma unroll
    for (int off = 32; off > 0; off >>= 1)
        v += __shfl_xor(v, off, 64);
    return v;
}

__device__ __forceinline__ float sigmoidf_(float x) {
    return 1.0f / (1.0f + __expf(-x));
}

__device__ __forceinline__ float dot4(float4 a, float4 b) {
    return fmaf(a.x, b.x, fmaf(a.y, b.y, fmaf(a.z, b.z, a.w * b.w)));
}

// K1: blocks [0,37): wave-per-h0-element. x in regs (broadcast), weight rows +
//     hn0 prefetched to regs (independent of l1); l1 -> LDS concurrently; ONE
//     syncthreads; gh0 has zero LDS dependency. blocks [37,146): gh1 rows,
//     no LDS, no sync. Block 37 resets the K2 counter.
__global__ __launch_bounds__(256) void k1_gru0(
    const float* __restrict__ si, const float* __restrict__ oi,
    const float* __restrict__ dst, const float* __restrict__ dob,
    const float* __restrict__ W1, const float* __restrict__ b1,
    const float* __restrict__ Wih0, const float* __restrict__ Whh0,
    const float* __restrict__ bih0, const float* __restrict__ bhh0,
    const float* __restrict__ Whh1, const float* __restrict__ bhh1,
    const float* __restrict__ hn,
    unsigned* __restrict__ ctr,
    float* __restrict__ h0g, float* __restrict__ gh1g)
{
    const int tid = threadIdx.x;
    const int wid = tid >> 6, lane = tid & 63;
    const bool t3 = (lane < 17);    // third scalar slot: 145 = 64+64+17

    if (blockIdx.x < NB_H0) {
        __shared__ __align__(16) float sl1[H1];
        const int e   = blockIdx.x * 4 + wid;
        const bool act = (e < GRUH);
        const int ee  = act ? e : (GRUH - 1);    // clamp for safe speculative loads

        // ---- prefetch: Whh0 rows + hn0 (gh0 path, reg-only) ----
        const float* wr0 = Whh0 + (ee           ) * GRUH;
        const float* wr1 = Whh0 + (ee +   GRUH  ) * GRUH;
        const float* wr2 = Whh0 + (ee + 2 * GRUH) * GRUH;
        const float h_a = hn[lane], h_b = hn[lane + 64], h_c = t3 ? hn[lane + 128] : 0.f;
        const float w00 = wr0[lane], w01 = wr0[lane + 64], w02 = t3 ? wr0[lane + 128] : 0.f;
        const float w10 = wr1[lane], w11 = wr1[lane + 64], w12 = t3 ? wr1[lane + 128] : 0.f;
        const float w20 = wr2[lane], w21 = wr2[lane + 64], w22 = t3 ? wr2[lane + 128] : 0.f;

        // ---- prefetch: Wih0 rows as float4 (row stride 2240B, 16B-aligned) ----
        const bool f3 = (lane < 12);             // 560/4 = 140 = 64+64+12
        const float4 z4 = make_float4(0.f, 0.f, 0.f, 0.f);
        const float4* p0 = reinterpret_cast<const float4*>(Wih0 + (ee           ) * H1);
        const float4* p1 = reinterpret_cast<const float4*>(Wih0 + (ee +   GRUH  ) * H1);
        const float4* p2 = reinterpret_cast<const float4*>(Wih0 + (ee + 2 * GRUH) * H1);
        const float4 q00 = p0[lane], q01 = p0[lane + 64], q02 = f3 ? p0[lane + 128] : z4;
        const float4 q10 = p1[lane], q11 = p1[lane + 64], q12 = f3 ? p1[lane + 128] : z4;
        const float4 q20 = p2[lane], q21 = p2[lane + 64], q22 = f3 ? p2[lane + 128] : z4;

        // ---- prefetch: biases + hn[e] (broadcast) ----
        const float bi0 = bih0[ee], bi1 = bih0[ee + GRUH], bi2 = bih0[ee + 2 * GRUH];
        const float bh0 = bhh0[ee], bh1 = bhh0[ee + GRUH], bh2 = bhh0[ee + 2 * GRUH];
        const float hne = hn[ee];

        // ---- x into regs (broadcast loads, no LDS) ----
        float x[14];
#pragma unroll
        for (int k = 0; k < 5; ++k) x[k] = si[k];
        x[5] = oi[0]; x[6] = oi[1];
#pragma unroll
        for (int k = 0; k < 5; ++k) x[7 + k] = dst[k];
        x[12] = dob[0]; x[13] = dob[1];

        // ---- l1 = relu(W1 @ x + b1) -> LDS ----
        for (int j = tid; j < H1; j += 256) {
            float a = b1[j];
            const float* wp = W1 + j * 14;
#pragma unroll
            for (int k = 0; k < 14; ++k) a = fmaf(wp[k], x[k], a);
            sl1[j] = fmaxf(a, 0.0f);
        }

        // ---- gh0 (pure registers, overlaps l1) ----
        float a3 = fmaf(w00, h_a, fmaf(w01, h_b, w02 * h_c));
        float a4 = fmaf(w10, h_a, fmaf(w11, h_b, w12 * h_c));
        float a5 = fmaf(w20, h_a, fmaf(w21, h_b, w22 * h_c));

        __syncthreads();

        // ---- gi0 from prefetched regs x LDS float4 ----
        const float4 s0 = *reinterpret_cast<const float4*>(&sl1[4 * lane]);
        const float4 s1 = *reinterpret_cast<const float4*>(&sl1[4 * (lane + 64)]);
        const float4 s2 = f3 ? *reinterpret_cast<const float4*>(&sl1[4 * (lane + 128)]) : z4;
        float a0 = dot4(q00, s0) + dot4(q01, s1) + dot4(q02, s2);
        float a1 = dot4(q10, s0) + dot4(q11, s1) + dot4(q12, s2);
        float a2 = dot4(q20, s0) + dot4(q21, s1) + dot4(q22, s2);

        a0 = wave_reduce(a0); a1 = wave_reduce(a1); a2 = wave_reduce(a2);
        a3 = wave_reduce(a3); a4 = wave_reduce(a4); a5 = wave_reduce(a5);
        if (lane == 0 && act) {
            const float r = sigmoidf_(a0 + bi0 + a3 + bh0);
            const float z = sigmoidf_(a1 + bi1 + a4 + bh1);
            const float n = tanhf   (a2 + bi2 + r * (a5 + bh2));
            h0g[e] = (1.0f - z) * n + z * hne;
        }
    } else {
        if (blockIdx.x == NB_H0 && tid == 0)
            __hip_atomic_store(ctr, 0u, __ATOMIC_RELAXED, __HIP_MEMORY_SCOPE_AGENT);
        const int r   = (blockIdx.x - NB_H0) * 4 + wid;
        const bool act = (r < G3);
        const int rr  = act ? r : (G3 - 1);
        const float* rp = Whh1 + rr * GRUH;
        const float wa = rp[lane], wb = rp[lane + 64], wc = t3 ? rp[lane + 128] : 0.f;
        const float ha = hn[GRUH + lane], hb = hn[GRUH + lane + 64],
                    hc = t3 ? hn[GRUH + lane + 128] : 0.f;
        const float bb = bhh1[rr];
        float a = fmaf(wa, ha, fmaf(wb, hb, wc * hc));
        a = wave_reduce(a);
        if (lane == 0 && act) gh1g[r] = a + bb;
    }
}

// K2: 37 blocks x 256. Wave-per-element h1, h0g read directly (coalesced, no
// LDS stage). Per-element RELEASE stores; one fetch_add(ACQ_REL); last block
// (no spinning) prefetches W2a/W2b while branching, acquires h1, runs head.
__global__ __launch_bounds__(256) void k2_gru1_head(
    const float* __restrict__ Wih1, const float* __restrict__ bih1,
    const float* __restrict__ W2a, const float* __restrict__ b2a,
    const float* __restrict__ W2b, const float* __restrict__ b2b,
    const float* __restrict__ hn,
    const float* __restrict__ h0g, const float* __restrict__ gh1g,
    unsigned* __restrict__ ctr,
    float* __restrict__ h1g, float* __restrict__ out)
{
    __shared__ float sh1[GRUH];
    __shared__ float sl2h[H2];
    __shared__ unsigned slast;

    const int tid = threadIdx.x;
    const int wid = tid >> 6, lane = tid & 63;
    const bool t3 = (lane < 17);
    const int e   = blockIdx.x * 4 + wid;
    const bool act = (e < GRUH);
    const int ee  = act ? e : (GRUH - 1);

    // ---- prefetch Wih1 rows + gh1 + biases + hn1[e] ----
    const float* r0 = Wih1 + (ee           ) * GRUH;
    const float* r1 = Wih1 + (ee +   GRUH  ) * GRUH;
    const float* r2 = Wih1 + (ee + 2 * GRUH) * GRUH;
    const float w0a = r0[lane], w0b = r0[lane + 64], w0c = t3 ? r0[lane + 128] : 0.f;
    const float w1a = r1[lane], w1b = r1[lane + 64], w1c = t3 ? r1[lane + 128] : 0.f;
    const float w2a = r2[lane], w2b = r2[lane + 64], w2c = t3 ? r2[lane + 128] : 0.f;
    const float g0 = gh1g[ee], g1 = gh1g[ee + GRUH], g2 = gh1g[ee + 2 * GRUH];
    const float bi0 = bih1[ee], bi1 = bih1[ee + GRUH], bi2 = bih1[ee + 2 * GRUH];
    const float hne = hn[GRUH + ee];

    // ---- h0 read: coalesced global, no LDS stage ----
    const float x0 = h0g[lane], x1 = h0g[lane + 64], x2 = t3 ? h0g[lane + 128] : 0.f;

    float c0 = fmaf(w0a, x0, fmaf(w0b, x1, w0c * x2));
    float c1 = fmaf(w1a, x0, fmaf(w1b, x1, w1c * x2));
    float c2 = fmaf(w2a, x0, fmaf(w2b, x1, w2c * x2));
    c0 = wave_reduce(c0); c1 = wave_reduce(c1); c2 = wave_reduce(c2);
    if (lane == 0 && act) {
        const float r = sigmoidf_(c0 + bi0 + g0);
        const float z = sigmoidf_(c1 + bi1 + g1);
        const float n = tanhf   (c2 + bi2 + r * g2);
        const float v = (1.0f - z) * n + z * hne;
        __hip_atomic_store(&h1g[e], v, __ATOMIC_RELEASE, __HIP_MEMORY_SCOPE_AGENT);
    }
    __syncthreads();
    if (tid == 0) {
        const unsigned old =
            __hip_atomic_fetch_add(ctr, 1u, __ATOMIC_ACQ_REL, __HIP_MEMORY_SCOPE_AGENT);
        slast = (old == NB_K2 - 1u) ? 1u : 0u;
    }

    // ---- prefetch head weights (in flight while slast resolves; read-only
    //      data so no coherence concern; non-last blocks just exit) ----
    float wa[10][3];
    const int rbase = wid * 10;
#pragma unroll
    for (int m = 0; m < 10; ++m) {
        const float* rp = W2a + (rbase + m) * GRUH;
        wa[m][0] = rp[lane];
        wa[m][1] = rp[lane + 64];
        wa[m][2] = t3 ? rp[lane + 128] : 0.f;
    }
    float ba[10];
#pragma unroll
    for (int m = 0; m < 10; ++m) ba[m] = b2a[rbase + m];
    float wb2[H2], bb2 = 0.f;
    if (tid < X_DIM * Y_DIM) {
        const float* rp = W2b + tid * H2;
#pragma unroll
        for (int k = 0; k < H2; ++k) wb2[k] = rp[k];
        bb2 = b2b[tid];
    }

    __syncthreads();
    if (!slast) return;

    // ---- last block only: stage h1 (acquire) and run the l2 head ----
    for (int j = tid; j < GRUH; j += 256)
        sh1[j] = __hip_atomic_load(&h1g[j], __ATOMIC_ACQUIRE, __HIP_MEMORY_SCOPE_AGENT);
    __syncthreads();

    const float ya = sh1[lane], yb = sh1[lane + 64], yc = t3 ? sh1[lane + 128] : 0.f;
#pragma unroll
    for (int m = 0; m < 10; ++m) {
        float a = fmaf(wa[m][0], ya, fmaf(wa[m][1], yb, wa[m][2] * yc));
        a = wave_reduce(a);
        if (lane == 0) sl2h[rbase + m] = fmaxf(a + ba[m], 0.0f);
    }
    __syncthreads();
    if (tid < X_DIM * Y_DIM) {
        float a = bb2;
#pragma unroll
        for (int k = 0; k < H2; ++k) a = fmaf(wb2[k], sl2h[k], a);
        out[tid] = a;
    }
}

extern "C" void kernel_launch(void* const* d_in, const int* in_sizes, int n_in,
                              void* d_out, int out_size, void* d_ws, size_t ws_size,
                              hipStream_t stream) {
    const float* si   = (const float*)d_in[0];
    const float* oi   = (const float*)d_in[1];
    const float* dst  = (const float*)d_in[2];
    const float* dob  = (const float*)d_in[3];
    const float* W1   = (const float*)d_in[4];
    const float* b1   = (const float*)d_in[5];
    const float* Wih0 = (const float*)d_in[6];
    const float* Whh0 = (const float*)d_in[7];
    const float* bih0 = (const float*)d_in[8];
    const float* bhh0 = (const float*)d_in[9];
    const float* Wih1 = (const float*)d_in[10];
    const float* Whh1 = (const float*)d_in[11];
    const float* bih1 = (const float*)d_in[12];
    const float* bhh1 = (const float*)d_in[13];
    const float* W2a  = (const float*)d_in[14];
    const float* b2a  = (const float*)d_in[15];
    const float* W2b  = (const float*)d_in[16];
    const float* b2b  = (const float*)d_in[17];
    const float* hn   = (const float*)d_in[18];

    float* ws = (float*)d_ws;
    unsigned* ctr = (unsigned*)d_ws;   // 1 cache line
    float* h0g  = ws + 64;             // 145 floats
    float* gh1g = ws + 64 + 256;       // 435 floats
    float* h1g  = ws + 64 + 256 + 512; // 145 floats

    hipLaunchKernelGGL(k1_gru0, dim3(NB_H0 + NB_GH1), dim3(256), 0, stream,
                       si, oi, dst, dob, W1, b1, Wih0, Whh0, bih0, bhh0,
                       Whh1, bhh1, hn, ctr, h0g, gh1g);
    hipLaunchKernelGGL(k2_gru1_head, dim3(NB_K2), dim3(256), 0, stream,
                       Wih1, bih1, W2a, b2a, W2b, b2b, hn, h0g, gh1g,
                       ctr, h1g, (float*)d_out);
}